// Round 4
// baseline (10952.968 us; speedup 1.0000x reference)
//
#include <hip/hip_runtime.h>
#include <cmath>

// Problem constants (fixed by the reference).
#define SEQ   4096
#define INP   1024
#define HID   1024
#define G4    4096   // 4*HID

typedef float f32x2 __attribute__((ext_vector_type(2)));

// ---------------------------------------------------------------------------
// Kernel 1: xg[t][r] = dot(emb[inputs[t]], W_ih[r]) + b_ih[r] + b_hh[r]
// 64x64 output tile per block, 256 threads, 4x4 micro-tile, fp32 VALU.
// (R0 version, proven ~740us; fusion reverted — R3 showed producer traffic
// slows the mailbox chain by more than the serial GEMM costs.)
// ---------------------------------------------------------------------------
__global__ __launch_bounds__(256) void xg_gemm_kernel(
    const int* __restrict__ inputs,
    const float* __restrict__ emb,
    const float* __restrict__ W_ih,
    const float* __restrict__ b_ih,
    const float* __restrict__ b_hh,
    float* __restrict__ xg)
{
    __shared__ __align__(16) float As[16][68];
    __shared__ __align__(16) float Bs[16][68];
    __shared__ int toks[64];

    const int tid = threadIdx.x;
    const int bt = blockIdx.y * 64;
    const int br = blockIdx.x * 64;

    if (tid < 64) toks[tid] = inputs[bt + tid];
    __syncthreads();

    const int tx = tid & 15;
    const int ty = tid >> 4;
    const int si = tid >> 2;
    const int sk = (tid & 3) * 4;

    float acc[4][4] = {};

    for (int kk = 0; kk < INP; kk += 16) {
        float4 av = *(const float4*)(emb  + (size_t)toks[si] * INP + kk + sk);
        float4 bv = *(const float4*)(W_ih + (size_t)(br + si) * INP + kk + sk);
        As[sk+0][si] = av.x; As[sk+1][si] = av.y; As[sk+2][si] = av.z; As[sk+3][si] = av.w;
        Bs[sk+0][si] = bv.x; Bs[sk+1][si] = bv.y; Bs[sk+2][si] = bv.z; Bs[sk+3][si] = bv.w;
        __syncthreads();
        #pragma unroll
        for (int k = 0; k < 16; ++k) {
            float4 a = *(const float4*)&As[k][ty * 4];
            float4 b = *(const float4*)&Bs[k][tx * 4];
            float ar[4] = {a.x, a.y, a.z, a.w};
            float brr[4] = {b.x, b.y, b.z, b.w};
            #pragma unroll
            for (int iy = 0; iy < 4; ++iy)
                #pragma unroll
                for (int ix = 0; ix < 4; ++ix)
                    acc[iy][ix] += ar[iy] * brr[ix];
        }
        __syncthreads();
    }

    const int r0 = br + tx * 4;
    float4 bias;
    bias.x = b_ih[r0+0] + b_hh[r0+0];
    bias.y = b_ih[r0+1] + b_hh[r0+1];
    bias.z = b_ih[r0+2] + b_hh[r0+2];
    bias.w = b_ih[r0+3] + b_hh[r0+3];
    #pragma unroll
    for (int iy = 0; iy < 4; ++iy) {
        float4 o;
        o.x = acc[iy][0] + bias.x;
        o.y = acc[iy][1] + bias.y;
        o.z = acc[iy][2] + bias.z;
        o.w = acc[iy][3] + bias.w;
        *(float4*)(xg + (size_t)(bt + ty * 4 + iy) * G4 + r0) = o;
    }
}

// ---------------------------------------------------------------------------
__device__ __forceinline__ float fast_sigmoid(float x) {
    x = fminf(fmaxf(x, -30.f), 30.f);
    return __builtin_amdgcn_rcpf(1.0f + __expf(-x));
}
__device__ __forceinline__ float fast_tanh(float x) {
    x = fminf(fmaxf(x, -15.f), 15.f);
    float e = __expf(2.0f * x);
    return (e - 1.0f) * __builtin_amdgcn_rcpf(e + 1.0f);
}

__device__ __forceinline__ unsigned long long mb_load(const unsigned long long* p) {
    return __hip_atomic_load(p, __ATOMIC_RELAXED, __HIP_MEMORY_SCOPE_AGENT);
}

// DPP cross-lane move (VALU pipe, not LDS). CTRL: 0xB1=xor1 (quad_perm
// [1,0,3,2]), 0x4E=xor2 ([2,3,0,1]), 0x124=row_ror:4, 0x128=row_ror:8.
template <int CTRL>
__device__ __forceinline__ float dpp_mov(float x) {
    return __int_as_float(__builtin_amdgcn_update_dpp(
        0, __float_as_int(x), CTRL, 0xF, 0xF, true));
}

// ---------------------------------------------------------------------------
// Kernel 2: persistent cooperative LSTM scan — 64 WGs x 512 threads.
//
// R4 geometry change (from R1's 64x1024): 2 waves/SIMD instead of 4.
// R1's counters showed ~2350cy/step of VALU issue per SIMD (4 waves
// serializing on the issue port) AND VGPR_Count=52 (weights parked in
// AGPRs -> ~64 v_accvgpr_reads/thread/step of extra issue). With 512
// threads (launch_bounds(512,2) -> 256-VGPR budget) each wave owns TWO
// h elements (8 gate rows, 128 weights = 64 f32x2 truly in VGPRs); the
// per-wave overhead (poll, reduction, barriers) is amortized over 2x
// the work and per-SIMD issue drops ~40%.
//
// Mailbox structure unchanged from R1 (proven): hbuf[parity(2)][1024] u64
// (tag<<32 | f32bits); wave 0 lanes 0..15 publish the WG's 16 entries as
// two full 64B lines; each thread polls its 2 slots (tid, tid+512),
// 2-deep pipelined. Slot-reuse safety: parity + tag as before.
// ---------------------------------------------------------------------------
__global__ __launch_bounds__(512, 2) void lstm_kernel(
    const float* __restrict__ xg,
    const float* __restrict__ W_hh,
    const float* __restrict__ h0,
    const float* __restrict__ c0,
    unsigned long long* __restrict__ hbuf,   // 2 * 1024 entries
    float* __restrict__ out)
{
    const int w    = blockIdx.x;   // 0..63
    const int tid  = threadIdx.x;  // 0..511
    const int lane = tid & 63;
    const int wv   = tid >> 6;     // wave 0..7 -> elements j0, j0+1
    const int qq   = lane >> 4;    // 16-lane group 0..3 (h-slice quarter)
    const int kc   = lane & 15;    // 64-float h chunk index
    const int ww0  = 2 * wv;       // element index within WG (0..15), even
    const int ww1  = ww0 + 1;
    const int j0   = w * 16 + ww0;
    const int j1   = j0 + 1;

    // Seed h0 with tag 0 (parity 0): wave 0 lanes 0..15, full-line store.
    if (wv == 0 && lane < 16) {
        unsigned long long pk =
            (unsigned long long)__float_as_uint(h0[w * 16 + lane]);
        __hip_atomic_store(hbuf + w * 16 + lane, pk,
                           __ATOMIC_RELAXED, __HIP_MEMORY_SCOPE_AGENT);
    }

    // Persistent W fragments for both owned elements, gate-paired for
    // v_pk_fma_f32: wA01[e] = {W_hh[0*H+j0][o+e], W_hh[1*H+j0][o+e]} etc.
    // o = kc*64 + qq*16. 64 f32x2 = 128 VGPRs, register-resident.
    f32x2 wA01[16], wA23[16], wB01[16], wB23[16];
    {
        const int o = kc * 64 + qq * 16;
        const float* r0A = W_hh + (size_t)(0 * HID + j0) * HID + o;
        const float* r1A = W_hh + (size_t)(1 * HID + j0) * HID + o;
        const float* r2A = W_hh + (size_t)(2 * HID + j0) * HID + o;
        const float* r3A = W_hh + (size_t)(3 * HID + j0) * HID + o;
        const float* r0B = W_hh + (size_t)(0 * HID + j1) * HID + o;
        const float* r1B = W_hh + (size_t)(1 * HID + j1) * HID + o;
        const float* r2B = W_hh + (size_t)(2 * HID + j1) * HID + o;
        const float* r3B = W_hh + (size_t)(3 * HID + j1) * HID + o;
        #pragma unroll
        for (int m = 0; m < 4; ++m) {
            float4 a0 = *(const float4*)(r0A + 4 * m);
            float4 a1 = *(const float4*)(r1A + 4 * m);
            float4 a2 = *(const float4*)(r2A + 4 * m);
            float4 a3 = *(const float4*)(r3A + 4 * m);
            wA01[4*m+0] = (f32x2){a0.x, a1.x}; wA23[4*m+0] = (f32x2){a2.x, a3.x};
            wA01[4*m+1] = (f32x2){a0.y, a1.y}; wA23[4*m+1] = (f32x2){a2.y, a3.y};
            wA01[4*m+2] = (f32x2){a0.z, a1.z}; wA23[4*m+2] = (f32x2){a2.z, a3.z};
            wA01[4*m+3] = (f32x2){a0.w, a1.w}; wA23[4*m+3] = (f32x2){a2.w, a3.w};
            float4 b0 = *(const float4*)(r0B + 4 * m);
            float4 b1 = *(const float4*)(r1B + 4 * m);
            float4 b2 = *(const float4*)(r2B + 4 * m);
            float4 b3 = *(const float4*)(r3B + 4 * m);
            wB01[4*m+0] = (f32x2){b0.x, b1.x}; wB23[4*m+0] = (f32x2){b2.x, b3.x};
            wB01[4*m+1] = (f32x2){b0.y, b1.y}; wB23[4*m+1] = (f32x2){b2.y, b3.y};
            wB01[4*m+2] = (f32x2){b0.z, b1.z}; wB23[4*m+2] = (f32x2){b2.z, b3.z};
            wB01[4*m+3] = (f32x2){b0.w, b1.w}; wB23[4*m+3] = (f32x2){b2.w, b3.w};
        }
    }

    float cA = c0[j0];
    float cB = c0[j1];

    __shared__ __align__(16) float hs[16 * 68];  // h chunks, stride 68
    __shared__ float xgs[64];                    // xg: gate q, elem ww -> q*16+ww
    __shared__ float hout[16];                   // this WG's 16 new h values

    // This thread's 2 polled elements: e0 = tid (chunk tid>>6),
    // e1 = tid+512 (chunk 8 + (tid>>6)); offset e&63 = tid&63 for both.
    const int lofsA = (tid >> 6) * 68 + (tid & 63);
    const int lofsB = (8 + (tid >> 6)) * 68 + (tid & 63);
    const bool hasx = (tid < 64);
    const size_t xgofs = (size_t)(tid >> 4) * HID + w * 16 + (tid & 15);
    const float* hp = hs + kc * 68 + qq * 16;    // private 16-elem slice

    for (int t = 0; t < SEQ; ++t) {
        const int par = t & 1;
        const unsigned long long* s0 = hbuf + (size_t)par * 1024 + tid;
        const unsigned long long* s1 = s0 + 512;

        // xg load issued before the poll; latency hides under the wait.
        float xv = 0.f;
        if (hasx) xv = xg[(size_t)t * G4 + xgofs];

        // 2-slot poll, 2-deep pipelined per slot (4 loads in flight).
        const unsigned int tg = (unsigned int)t;
        unsigned long long v0, v1;
        {
            unsigned long long p0 = mb_load(s0), q0 = mb_load(s0);
            unsigned long long p1 = mb_load(s1), q1 = mb_load(s1);
            unsigned ok = 0;
            for (;;) {
                if (!(ok & 1u)) { if ((unsigned)(p0 >> 32) == tg) { v0 = p0; ok |= 1u; } else p0 = mb_load(s0); }
                if (!(ok & 2u)) { if ((unsigned)(p1 >> 32) == tg) { v1 = p1; ok |= 2u; } else p1 = mb_load(s1); }
                if (ok == 3u) break;
                if (!(ok & 1u)) { if ((unsigned)(q0 >> 32) == tg) { v0 = q0; ok |= 1u; } else q0 = mb_load(s0); }
                if (!(ok & 2u)) { if ((unsigned)(q1 >> 32) == tg) { v1 = q1; ok |= 2u; } else q1 = mb_load(s1); }
                if (ok == 3u) break;
            }
        }

        hs[lofsA] = __uint_as_float((unsigned)v0);
        hs[lofsB] = __uint_as_float((unsigned)v1);
        if (hasx) xgs[tid] = xv;
        __syncthreads();  // B1

        // Packed partial dots: 4 f32x2 accumulators (elemA gates 01|23,
        // elemB gates 01|23) over the private 16-elem slice: 64 pk-FMA.
        f32x2 pA01 = {0.f, 0.f}, pA23 = {0.f, 0.f};
        f32x2 pB01 = {0.f, 0.f}, pB23 = {0.f, 0.f};
        #pragma unroll
        for (int m = 0; m < 4; ++m) {
            float4 hv = *(const float4*)(hp + 4 * m);
            float hvs[4] = {hv.x, hv.y, hv.z, hv.w};
            #pragma unroll
            for (int s = 0; s < 4; ++s) {
                f32x2 hb = {hvs[s], hvs[s]};
                pA01 += wA01[4*m+s] * hb;
                pA23 += wA23[4*m+s] * hb;
                pB01 += wB01[4*m+s] * hb;
                pB23 += wB23[4*m+s] * hb;
            }
        }
        float p[8] = {pA01.x, pA01.y, pA23.x, pA23.y,
                      pB01.x, pB01.y, pB23.x, pB23.y};

        // 64-lane butterfly reduction of the 8 accumulators.
        // xor1, xor2, ror4, ror8: DPP (VALU); xor16/xor32: LDS bpermute.
        #pragma unroll
        for (int q = 0; q < 8; ++q) {
            p[q] += dpp_mov<0xB1>(p[q]);
            p[q] += dpp_mov<0x4E>(p[q]);
            p[q] += dpp_mov<0x124>(p[q]);
            p[q] += dpp_mov<0x128>(p[q]);
            p[q] += __shfl_xor(p[q], 16);
            p[q] += __shfl_xor(p[q], 32);
        }

        float giA = p[0] + xgs[ 0 + ww0];
        float gfA = p[1] + xgs[16 + ww0];
        float ggA = p[2] + xgs[32 + ww0];
        float goA = p[3] + xgs[48 + ww0];
        float giB = p[4] + xgs[ 0 + ww1];
        float gfB = p[5] + xgs[16 + ww1];
        float ggB = p[6] + xgs[32 + ww1];
        float goB = p[7] + xgs[48 + ww1];

        float igA = fast_sigmoid(giA);
        float fgA = fast_sigmoid(gfA);
        float gcA = fast_tanh(ggA);
        float ogA = fast_sigmoid(goA);
        cA = fgA * cA + igA * gcA;
        float hA = ogA * fast_tanh(cA);

        float igB = fast_sigmoid(giB);
        float fgB = fast_sigmoid(gfB);
        float gcB = fast_tanh(ggB);
        float ogB = fast_sigmoid(goB);
        cB = fgB * cB + igB * gcB;
        float hB = ogB * fast_tanh(cB);

        if (lane == 0) { hout[ww0] = hA; hout[ww1] = hB; }
        __syncthreads();  // B2

        // Wave 0, lanes 0..15: publish 16 tagged entries -> two full 64B lines.
        if (wv == 0 && lane < 16) {
            unsigned long long pk =
                ((unsigned long long)(unsigned int)(t + 1) << 32) |
                (unsigned long long)__float_as_uint(hout[lane]);
            __hip_atomic_store(
                hbuf + (size_t)((t + 1) & 1) * 1024 + w * 16 + lane, pk,
                __ATOMIC_RELAXED, __HIP_MEMORY_SCOPE_AGENT);
        }
        // hs/xgs single buffer safe: next step's writes ordered after B2.
    }

    // ------------------- final log_softmax (WG 0 only) -------------------
    if (w != 0) return;

    // Each thread holds elements tid and tid+512 (tag SEQ, parity 0).
    const unsigned int tgf = (unsigned int)SEQ;
    float a0, a1;
    {
        unsigned long long v;
        do { v = mb_load(hbuf + tid);       } while ((unsigned)(v >> 32) != tgf);
        a0 = __uint_as_float((unsigned)v);
        do { v = mb_load(hbuf + tid + 512); } while ((unsigned)(v >> 32) != tgf);
        a1 = __uint_as_float((unsigned)v);
    }

    // 64-lane butterfly per 64-element group, then serial combine over the
    // 16 groups in order (same order as previous rounds).
    __shared__ float rmax[16];
    __shared__ float rsum[16];

    float m0 = a0, m1 = a1;
    #pragma unroll
    for (int d = 1; d < 64; d <<= 1) {
        m0 = fmaxf(m0, __shfl_xor(m0, d));
        m1 = fmaxf(m1, __shfl_xor(m1, d));
    }
    if (lane == 0) {
        rmax[wv    ] = m0;
        rmax[wv + 8] = m1;
    }
    __syncthreads();
    float gm = rmax[0];
    #pragma unroll
    for (int i = 1; i < 16; ++i) gm = fmaxf(gm, rmax[i]);

    float s0 = expf(a0 - gm), s1 = expf(a1 - gm);
    #pragma unroll
    for (int d = 1; d < 64; d <<= 1) {
        s0 += __shfl_xor(s0, d);
        s1 += __shfl_xor(s1, d);
    }
    if (lane == 0) {
        rsum[wv    ] = s0;
        rsum[wv + 8] = s1;
    }
    __syncthreads();
    float tot = rsum[0];
    #pragma unroll
    for (int i = 1; i < 16; ++i) tot += rsum[i];
    const float lse = gm + logf(tot);

    out[tid      ] = a0 - lse;
    out[tid + 512] = a1 - lse;
}

// ---------------------------------------------------------------------------
extern "C" void kernel_launch(void* const* d_in, const int* in_sizes, int n_in,
                              void* d_out, int out_size, void* d_ws, size_t ws_size,
                              hipStream_t stream)
{
    const int*   inputs = (const int*)d_in[0];
    const float* emb    = (const float*)d_in[1];
    const float* W_ih   = (const float*)d_in[2];
    const float* W_hh   = (const float*)d_in[3];
    const float* b_ih   = (const float*)d_in[4];
    const float* b_hh   = (const float*)d_in[5];
    const float* h0     = (const float*)d_in[6];
    const float* c0     = (const float*)d_in[7];
    float* out = (float*)d_out;

    // Workspace: [0, 64MB) xg ; [64MB, +16KB) hbuf (2 x 1024 u64).
    float* xg = (float*)d_ws;
    unsigned long long* hbuf =
        (unsigned long long*)((char*)d_ws + (size_t)SEQ * G4 * sizeof(float));

    dim3 g1(G4 / 64, SEQ / 64), b1(256);
    hipLaunchKernelGGL(xg_gemm_kernel, g1, b1, 0, stream,
                       inputs, emb, W_ih, b_ih, b_hh, xg);

    void* args[] = { (void*)&xg, (void*)&W_hh, (void*)&h0, (void*)&c0,
                     (void*)&hbuf, (void*)&out };
    hipLaunchCooperativeKernel((void*)lstm_kernel, dim3(64), dim3(512),
                               args, 0u, stream);
}